// Round 6
// baseline (805.766 us; speedup 1.0000x reference)
//
#include <hip/hip_runtime.h>
#include <hip/hip_bf16.h>
#include <stdint.h>

typedef __bf16 bf16_t;
typedef __bf16 bf16x8 __attribute__((ext_vector_type(8)));
typedef float floatx4 __attribute__((ext_vector_type(4)));
typedef uint32_t u32;

#define M_DIM 4096
#define K_DIM 4096
#define N_DIM 11008
#define GRP 128
#define NHALF (N_DIM / 2)              // 5504
#define NTILES (N_DIM / 16)            // 688
#define KB32 (K_DIM / 32)              // 128
#define WB_DWORDS (NTILES * KB32 * 64) // 5,636,096 dwords
#define WB_BYTES ((size_t)WB_DWORDS * 4)

// ---------------------------------------------------------------------------
// Repack: w_packed [K][N/2] (int32-widened uint8; low nibble = even n)
//   -> WB fragment-linear: dword ((ntile*KB32 + k0/32)*64 + lane), nibble j =
//      int4 at n = ntile*16 + (lane&15), k = (k0/32)*32 + (lane>>4)*8 + j.
// ---------------------------------------------------------------------------
__global__ __launch_bounds__(256) void repack_w_kernel(const int* __restrict__ wp,
                                                       u32* __restrict__ WB) {
  const u32 o     = blockIdx.x * 256u + threadIdx.x;
  const u32 lane  = o & 63u;
  const u32 kblk  = (o >> 6) & (KB32 - 1);
  const u32 ntile = o >> 13;
  const u32 n     = ntile * 16u + (lane & 15u);
  const u32 nh    = n >> 1;
  const u32 sh    = (n & 1u) * 4u;  // even n -> low nibble
  const u32 kbase = kblk * 32u + (lane >> 4) * 8u;
  const int* src  = wp + (size_t)kbase * NHALF + nh;
  u32 d = 0;
#pragma unroll
  for (int j = 0; j < 8; ++j) {
    u32 v = (u32)src[(size_t)j * NHALF];
    d |= ((v >> sh) & 0xFu) << (4 * j);
  }
  WB[o] = d;
}

// ---------------------------------------------------------------------------
// Main GEMM: 128x128 tile, BK=64, 4 waves split N 1x4.
// x is FLOAT32 (harness upcasts fp16): stage 2x float4 -> cvt bf16 -> LDS.
// Output is FLOAT32.
// ---------------------------------------------------------------------------
__global__ __launch_bounds__(256) void gemm_int4_kernel(const float* __restrict__ x,
                                                        const u32* __restrict__ WB,
                                                        const float* __restrict__ wscale,
                                                        const float* __restrict__ wzero,
                                                        float* __restrict__ out) {
  __shared__ __align__(16) bf16_t As[128 * 64];  // 16 KB, [m][k]

  const u32 tid  = threadIdx.x;
  const u32 lane = tid & 63u;
  const u32 wave = tid >> 6;
  const u32 l15  = lane & 15u;
  const u32 quad = lane >> 4;

  const u32 n0 = blockIdx.x * 128u;
  const u32 m0 = blockIdx.y * 128u;

  // thread t stages rows (t>>3) + 32*it, float cols (t&7)*8 .. +7
  const float* xsrc = x + (m0 + (tid >> 3)) * (u32)K_DIM + (tid & 7u) * 8u;
  char* lds_dst = (char*)(&As[0]) + tid * 16u;

  const u32* wb_base = WB + ((n0 >> 4) + wave * 2u) * (u32)(KB32 * 64) + lane;
  const u32 n_idx    = n0 + wave * 32u + l15;

  const bf16_t* afrag_base = &As[0] + l15 * 64u + quad * 8u;

  floatx4 acc[8][2];
  floatx4 zero4 = {0.f, 0.f, 0.f, 0.f};
#pragma unroll
  for (int i = 0; i < 8; ++i)
#pragma unroll
    for (int t = 0; t < 2; ++t) acc[i][t] = zero4;

  float sc[2], zs[2];

  for (u32 kt = 0; kt < K_DIM / 64u; ++kt) {
    // ---- global loads for this tile into registers ----
    const float* src = xsrc + kt * 64u;
    bf16x8 av[4];
#pragma unroll
    for (int it = 0; it < 4; ++it) {
      float4 f0 = *(const float4*)(src + it * 32 * K_DIM);
      float4 f1 = *(const float4*)(src + it * 32 * K_DIM + 4);
      bf16x8 v;
      v[0] = (bf16_t)f0.x; v[1] = (bf16_t)f0.y; v[2] = (bf16_t)f0.z; v[3] = (bf16_t)f0.w;
      v[4] = (bf16_t)f1.x; v[5] = (bf16_t)f1.y; v[6] = (bf16_t)f1.z; v[7] = (bf16_t)f1.w;
      av[it] = v;
    }

    u32 bq[2][2];
#pragma unroll
    for (int ks = 0; ks < 2; ++ks)
#pragma unroll
      for (int t = 0; t < 2; ++t)
        bq[ks][t] = wb_base[(u32)(t * KB32 * 64) + (kt * 2u + ks) * 64u];

    if ((kt & 1u) == 0u) {  // group changes every 2 K-tiles (GRP=128, BK=64)
      const u32 g = kt >> 1;
#pragma unroll
      for (int t = 0; t < 2; ++t) {
        float s = wscale[g * N_DIM + n_idx + t * 16u];
        float z = wzero[g * N_DIM + n_idx + t * 16u];
        sc[t] = s;
        zs[t] = s * z;
      }
    }

    __syncthreads();  // all waves done READING As from previous iter
#pragma unroll
    for (int it = 0; it < 4; ++it)
      *(bf16x8*)(lds_dst + it * 4096) = av[it];
    __syncthreads();  // As tile visible to all waves

#pragma unroll
    for (int ks = 0; ks < 2; ++ks) {
      bf16x8 af[8];
#pragma unroll
      for (int i = 0; i < 8; ++i)
        af[i] = *(const bf16x8*)(afrag_base + i * 16 * 64 + ks * 32);
#pragma unroll
      for (int t = 0; t < 2; ++t) {
        bf16x8 bfr;
#pragma unroll
        for (int j = 0; j < 8; ++j) {
          float w = (float)((bq[ks][t] >> (4 * j)) & 0xFu) * sc[t] - zs[t];
          bfr[j] = (bf16_t)w;
        }
#pragma unroll
        for (int i = 0; i < 8; ++i)
          acc[i][t] = __builtin_amdgcn_mfma_f32_16x16x32_bf16(af[i], bfr, acc[i][t], 0, 0, 0);
      }
    }
  }

  // C/D layout: col = lane&15 (n), row = quad*4 + r (m)  [m89-verified]
  const u32 col0 = n0 + wave * 32u + l15;
  const u32 row0 = m0 + quad * 4u;
#pragma unroll
  for (int i = 0; i < 8; ++i)
#pragma unroll
    for (int t = 0; t < 2; ++t)
#pragma unroll
      for (int r = 0; r < 4; ++r)
        out[(row0 + i * 16u + r) * (u32)N_DIM + col0 + t * 16u] = acc[i][t][r];
}

// ---------------------------------------------------------------------------
// Fallback GEMM (no workspace): W bytes staged in LDS (stride 68).
// ---------------------------------------------------------------------------
__global__ __launch_bounds__(256) void gemm_int4_direct(const float* __restrict__ x,
                                                        const int* __restrict__ wp,
                                                        const float* __restrict__ wscale,
                                                        const float* __restrict__ wzero,
                                                        float* __restrict__ out) {
  __shared__ __align__(16) bf16_t As[128 * 64];
  __shared__ unsigned char Wb[64 * 68];

  const u32 tid  = threadIdx.x;
  const u32 lane = tid & 63u;
  const u32 wave = tid >> 6;
  const u32 l15  = lane & 15u;
  const u32 quad = lane >> 4;

  const u32 n0 = blockIdx.x * 128u;
  const u32 m0 = blockIdx.y * 128u;

  const float* xsrc = x + (m0 + (tid >> 3)) * (u32)K_DIM + (tid & 7u) * 8u;
  char* lds_dst = (char*)(&As[0]) + tid * 16u;

  const u32 wrow = tid >> 2;
  const u32 wcol = (tid & 3u) * 16;
  const int* wsrc = wp + (size_t)wrow * NHALF + (n0 >> 1) + wcol;

  const u32 n_idx = n0 + wave * 32u + l15;
  const u32 bcol0 = (wave * 32u + l15) >> 1;
  const u32 bcol1 = (wave * 32u + 16u + l15) >> 1;
  const u32 nsh   = (l15 & 1u) * 4u;

  floatx4 acc[8][2];
  floatx4 zero4 = {0.f, 0.f, 0.f, 0.f};
#pragma unroll
  for (int i = 0; i < 8; ++i)
#pragma unroll
    for (int t = 0; t < 2; ++t) acc[i][t] = zero4;

  const bf16_t* afrag_base = &As[0] + l15 * 64u + quad * 8u;
  float sc[2], zs[2];

  for (u32 kt = 0; kt < K_DIM / 64u; ++kt) {
    const float* src = xsrc + kt * 64u;
    bf16x8 av[4];
#pragma unroll
    for (int it = 0; it < 4; ++it) {
      float4 f0 = *(const float4*)(src + it * 32 * K_DIM);
      float4 f1 = *(const float4*)(src + it * 32 * K_DIM + 4);
      bf16x8 v;
      v[0] = (bf16_t)f0.x; v[1] = (bf16_t)f0.y; v[2] = (bf16_t)f0.z; v[3] = (bf16_t)f0.w;
      v[4] = (bf16_t)f1.x; v[5] = (bf16_t)f1.y; v[6] = (bf16_t)f1.z; v[7] = (bf16_t)f1.w;
      av[it] = v;
    }

    const int* wsk = wsrc + (size_t)kt * 64u * NHALF;
    int4 wv[4];
#pragma unroll
    for (int q = 0; q < 4; ++q) wv[q] = *(const int4*)(wsk + q * 4);

    if ((kt & 1u) == 0u) {
      const u32 g = kt >> 1;
#pragma unroll
      for (int t = 0; t < 2; ++t) {
        float s = wscale[g * N_DIM + n_idx + t * 16u];
        float z = wzero[g * N_DIM + n_idx + t * 16u];
        sc[t] = s;
        zs[t] = s * z;
      }
    }

    __syncthreads();
#pragma unroll
    for (int it = 0; it < 4; ++it)
      *(bf16x8*)(lds_dst + it * 4096) = av[it];
#pragma unroll
    for (int q = 0; q < 4; ++q) {
      u32 d = ((u32)wv[q].x & 0xFFu) | (((u32)wv[q].y & 0xFFu) << 8) |
              (((u32)wv[q].z & 0xFFu) << 16) | (((u32)wv[q].w & 0xFFu) << 24);
      *(u32*)(&Wb[wrow * 68u + wcol + q * 4u]) = d;
    }
    __syncthreads();

#pragma unroll
    for (int ks = 0; ks < 2; ++ks) {
      bf16x8 af[8];
#pragma unroll
      for (int i = 0; i < 8; ++i)
        af[i] = *(const bf16x8*)(afrag_base + i * 16 * 64 + ks * 32);
#pragma unroll
      for (int t = 0; t < 2; ++t) {
        const u32 bc = t ? bcol1 : bcol0;
        bf16x8 bfr;
#pragma unroll
        for (int j = 0; j < 8; ++j) {
          u32 byte = Wb[(ks * 32u + quad * 8u + j) * 68u + bc];
          float w = (float)((byte >> nsh) & 0xFu) * sc[t] - zs[t];
          bfr[j] = (bf16_t)w;
        }
#pragma unroll
        for (int i = 0; i < 8; ++i)
          acc[i][t] = __builtin_amdgcn_mfma_f32_16x16x32_bf16(af[i], bfr, acc[i][t], 0, 0, 0);
      }
    }
  }

  const u32 col0 = n0 + wave * 32u + l15;
  const u32 row0 = m0 + quad * 4u;
#pragma unroll
  for (int i = 0; i < 8; ++i)
#pragma unroll
    for (int t = 0; t < 2; ++t)
#pragma unroll
      for (int r = 0; r < 4; ++r)
        out[(row0 + i * 16u + r) * (u32)N_DIM + col0 + t * 16u] = acc[i][t][r];
}

extern "C" void kernel_launch(void* const* d_in, const int* in_sizes, int n_in,
                              void* d_out, int out_size, void* d_ws, size_t ws_size,
                              hipStream_t stream) {
  const float* x      = (const float*)d_in[0];   // fp16 ref -> fp32 on device
  const int*   wp     = (const int*)d_in[1];     // uint8 -> int32 on device
  const float* wscale = (const float*)d_in[2];   // fp16 ref -> fp32
  const float* wzero  = (const float*)d_in[3];   // fp16 ref -> fp32
  float*       out    = (float*)d_out;           // fp16 ref output -> fp32

  if (ws_size >= WB_BYTES && d_ws != nullptr) {
    u32* WB = (u32*)d_ws;
    repack_w_kernel<<<WB_DWORDS / 256, 256, 0, stream>>>(wp, WB);
    gemm_int4_kernel<<<dim3(N_DIM / 128, M_DIM / 128), 256, 0, stream>>>(x, WB, wscale, wzero, out);
  } else {
    gemm_int4_direct<<<dim3(N_DIM / 128, M_DIM / 128), 256, 0, stream>>>(x, wp, wscale, wzero, out);
  }
}